// Round 1
// baseline (10651.768 us; speedup 1.0000x reference)
//
#include <hip/hip_runtime.h>
#include <math.h>

#define H 512
#define D2 1024
#define D4 2048
#define E 1024
#define V 32000
#define M 32
#define N 4096
#define L 64
#define G3 (3*D4)   // 6144

// workspace layout (float offsets)
#define WS_H        0                      // 1024
#define WS_UAH      1024                   // 1024
#define WS_HSEQ     2048                   // 65*2048 = 133120  (hseq[0]=d0 flat, hseq[t+1]=h_new_t)
#define WS_GIW      135168                 // 64*6144
#define WS_RW       528384                 // 64*1024
#define WS_GH       593920                 // 6144
#define WS_SPART    600064                 // 2 parities * 64
#define WS_RSEQ     600192                 // 64*512
#define WS_RT       632960                 // 512*64  (transposed r for logits GEMM)
#define WS_ANST     665728                 // 1024*64 (ans transposed)
#define WS_ROWMAX   731264                 // 64 (uint-encoded float)
#define WS_ROWSUM   731328                 // 64
#define WS_TOTAL    731392                 // ~2.93 MB

__device__ __forceinline__ float warpSum64(float v){
#pragma unroll
    for (int off = 32; off; off >>= 1) v += __shfl_xor(v, off, 64);
    return v;
}

__device__ __forceinline__ unsigned enc_f(float f){
    unsigned u = __float_as_uint(f);
    return (u & 0x80000000u) ? ~u : (u | 0x80000000u);
}
__device__ __forceinline__ float dec_f(unsigned u){
    return (u & 0x80000000u) ? __uint_as_float(u & 0x7fffffffu) : __uint_as_float(~u);
}

// ---------------- init: transpose ans, zero h, init rowmax/rowsum ----------------
__global__ void k_init(const float* __restrict__ ans, float* __restrict__ ws){
    int b = blockIdx.x;
    if (b < L){
        for (int j = threadIdx.x; j < E; j += blockDim.x)
            ws[WS_ANST + j*L + b] = ans[b*E + j];
    } else {
        for (int i = threadIdx.x; i < D2; i += blockDim.x) ws[WS_H + i] = 0.f;
        if (threadIdx.x < L){
            ((unsigned*)(ws + WS_ROWMAX))[threadIdx.x] = enc_f(-3.402823466e38f);
            ws[WS_ROWSUM + threadIdx.x] = 0.f;
        }
    }
}

// ---------------- h = colsum(h_q) + colsum(h_p) ----------------
__global__ void k_colsum(const float* __restrict__ hq, const float* __restrict__ hp,
                         float* __restrict__ ws){
    float4 acc = {0.f,0.f,0.f,0.f};
    int tid = threadIdx.x;   // 256 threads -> 1024 cols as float4
    for (int r = blockIdx.x; r < M + N; r += gridDim.x){
        const float* src = (r < M) ? (hq + (size_t)r*D2) : (hp + (size_t)(r-M)*D2);
        float4 v = ((const float4*)src)[tid];
        acc.x += v.x; acc.y += v.y; acc.z += v.z; acc.w += v.w;
    }
    float* h = ws + WS_H + tid*4;
    atomicAdd(h+0, acc.x); atomicAdd(h+1, acc.y);
    atomicAdd(h+2, acc.z); atomicAdd(h+3, acc.w);
}

// ---------------- u_a_h and d0 ----------------
__global__ void k_uah_d0(const float* __restrict__ uaw, const float* __restrict__ wdw,
                         const float* __restrict__ wdb, const float* __restrict__ hq,
                         const float* __restrict__ hp, float* __restrict__ ws){
    int wid = blockIdx.x * (blockDim.x >> 6) + (threadIdx.x >> 6); // 0..3071
    int lane = threadIdx.x & 63;
    const float* Wrow; const float* x;
    if (wid < D2){ Wrow = uaw + (size_t)wid*D2; x = ws + WS_H; }
    else {
        int i = (wid - D2) & 1023;
        int r = (wid - D2) >> 10;
        Wrow = wdw + (size_t)i*D2;
        x = r ? hp : hq;  // row 0 of each
    }
    float acc = 0.f;
#pragma unroll
    for (int m = 0; m < 16; m++){ int j = lane + 64*m; acc += Wrow[j] * x[j]; }
    acc = warpSum64(acc);
    if (lane == 0){
        if (wid < D2) ws[WS_UAH + wid] = acc;
        else {
            int i = (wid - D2) & 1023, r = (wid - D2) >> 10;
            ws[WS_HSEQ + r*D2 + i] = tanhf(acc + wdb[i]);
        }
    }
}

// ---------------- precompute GI_w[t][k] = W_ih[k,:1024]@w_t + b_ih[k]; R_w[t][i] = w_r[i]@w_t ----------------
__global__ void k_pregemm(const float* __restrict__ wih, const float* __restrict__ bih,
                          const float* __restrict__ wrw, float* __restrict__ ws){
    int wid = blockIdx.x * (blockDim.x >> 6) + (threadIdx.x >> 6); // 0..7167
    int lane = threadIdx.x & 63;  // lane = t
    const float* Wrow; float bias = 0.f;
    if (wid < G3){ Wrow = wih + (size_t)wid*D4; bias = bih[wid]; }
    else         { Wrow = wrw + (size_t)(wid - G3)*D2; }
    const float* ansT = ws + WS_ANST;
    float acc = 0.f;
    for (int j = 0; j < E; j += 4){
        float4 wv = *(const float4*)(Wrow + j);
        acc += wv.x * ansT[(j+0)*L + lane];
        acc += wv.y * ansT[(j+1)*L + lane];
        acc += wv.z * ansT[(j+2)*L + lane];
        acc += wv.w * ansT[(j+3)*L + lane];
    }
    acc += bias;
    if (wid < G3) ws[WS_GIW + (size_t)lane*G3 + wid] = acc;
    else          ws[WS_RW  + (size_t)lane*D2 + (wid - G3)] = acc;
}

// ---------------- per-step kernel 1: gh(t), s(t) partials, finalize r_{t-1} ----------------
__global__ void k_step_p1(const float* __restrict__ whh, const float* __restrict__ bhh,
                          const float* __restrict__ waw, const float* __restrict__ vw,
                          const float* __restrict__ urw, const float* __restrict__ vrw,
                          float* __restrict__ ws, int t){
    int nwaves = gridDim.x * (blockDim.x >> 6);
    int wid = blockIdx.x * (blockDim.x >> 6) + (threadIdx.x >> 6);
    int lane = threadIdx.x & 63;
    const float* hprev = ws + WS_HSEQ + (size_t)t*D4;
    int nA = (t < L) ? G3 : 0;
    int nB = (t < L) ? 64 : 0;
    int nC = (t > 0) ? 512 : 0;
    int ntask = nA + nB + nC;
    for (int task = wid; task < ntask; task += nwaves){
        if (task < nA){
            int k = task;
            const float* Wr = whh + (size_t)k*D4;
            float acc = 0.f;
#pragma unroll
            for (int m = 0; m < 32; m++){ int j = lane + 64*m; acc += Wr[j]*hprev[j]; }
            acc = warpSum64(acc);
            if (lane == 0) ws[WS_GH + k] = acc + bhh[k];
        } else if (task < nA + nB){
            int g = task - nA;
            int r  = g >> 5;
            int i0 = (g & 31) * 32;
            const float* d2r = hprev + r*D2;
            float part = 0.f;
            for (int ii = 0; ii < 32; ii++){
                int i = i0 + ii;
                const float* Wr = waw + (size_t)i*D2;
                float acc = 0.f;
#pragma unroll
                for (int m = 0; m < 16; m++){ int j = lane + 64*m; acc += Wr[j]*d2r[j]; }
                acc = warpSum64(acc);
                if (lane == 0) part += vw[i] * tanhf(acc + ws[WS_UAH + i]);
            }
            if (lane == 0) ws[WS_SPART + (t & 1)*64 + g] = part;
        } else {
            int h = task - nA - nB;   // 0..511, finalize r_{t-1}
            const float* d2p = ws + WS_HSEQ + (size_t)(t-1)*D4;
            const float* hn  = ws + WS_HSEQ + (size_t)t*D4;
            float sv = ws[WS_SPART + ((t-1) & 1)*64 + lane];
#pragma unroll
            for (int off = 16; off; off >>= 1) sv += __shfl_xor(sv, off, 64);
            float s0 = __shfl(sv, 0, 64), s1 = __shfl(sv, 32, 64);
            float mx = fmaxf(s0, s1);
            float e0 = expf(s0 - mx), e1 = expf(s1 - mx);
            float a0 = e0/(e0+e1), a1 = e1/(e0+e1);
            float acc1 = 0.f, acc2 = 0.f;
            const float* U1 = urw + (size_t)h*D2;
            const float* U2 = urw + (size_t)(h+H)*D2;
#pragma unroll
            for (int m = 0; m < 16; m++){
                int j = lane + 64*m;
                float c = a0*d2p[j] + a1*d2p[D2 + j];
                acc1 += U1[j]*c; acc2 += U2[j]*c;
            }
            const float* V1 = vrw + (size_t)h*D4;
            const float* V2 = vrw + (size_t)(h+H)*D4;
#pragma unroll
            for (int m = 0; m < 32; m++){
                int j = lane + 64*m;
                float hv = hn[j];
                acc1 += V1[j]*hv; acc2 += V2[j]*hv;
            }
            acc1 = warpSum64(acc1); acc2 = warpSum64(acc2);
            if (lane == 0){
                float r1 = ws[WS_RW + (size_t)(t-1)*D2 + h]     + acc1;
                float r2 = ws[WS_RW + (size_t)(t-1)*D2 + h + H] + acc2;
                float mo = fmaxf(r1, r2);
                ws[WS_RSEQ + (size_t)(t-1)*H + h] = mo;
                ws[WS_RT + (size_t)h*L + (t-1)]   = mo;
            }
        }
    }
}

// ---------------- per-step kernel 2: h_new(t) ----------------
__global__ void k_step_p2(const float* __restrict__ wih, float* __restrict__ ws, int t){
    __shared__ float cbuf[D2];
    __shared__ float sa[2];
    int tid = threadIdx.x;
    int lane = tid & 63, warp = tid >> 6;
    const float* hprev = ws + WS_HSEQ + (size_t)t*D4;
    if (warp == 0){
        float sv = ws[WS_SPART + (t & 1)*64 + lane];
#pragma unroll
        for (int off = 16; off; off >>= 1) sv += __shfl_xor(sv, off, 64);
        if (lane == 0)  sa[0] = sv;
        if (lane == 32) sa[1] = sv;
    }
    __syncthreads();
    float s0 = sa[0], s1 = sa[1];
    float mx = fmaxf(s0, s1);
    float e0 = expf(s0 - mx), e1 = expf(s1 - mx);
    float a0 = e0/(e0+e1), a1 = e1/(e0+e1);
    for (int j = tid; j < D2; j += blockDim.x)
        cbuf[j] = a0*hprev[j] + a1*hprev[D2 + j];
    __syncthreads();
    int k = blockIdx.x * (blockDim.x >> 6) + warp;  // 0..2047
    if (k < D4){
        const float* Wr = wih + (size_t)k*D4 + D2;
        const float* Wz = wih + (size_t)(k + D4)*D4 + D2;
        const float* Wn = wih + (size_t)(k + 2*D4)*D4 + D2;
        float ar = 0.f, az = 0.f, an = 0.f;
#pragma unroll
        for (int m = 0; m < 16; m++){
            int j = lane + 64*m;
            float c = cbuf[j];
            ar += Wr[j]*c; az += Wz[j]*c; an += Wn[j]*c;
        }
        ar = warpSum64(ar); az = warpSum64(az); an = warpSum64(an);
        if (lane == 0){
            const float* gi = ws + WS_GIW + (size_t)t*G3;
            const float* gh = ws + WS_GH;
            float rr = 1.f/(1.f + expf(-((gi[k]        + ar) + gh[k])));
            float zz = 1.f/(1.f + expf(-((gi[k + D4]   + az) + gh[k + D4])));
            float nn = tanhf((gi[k + 2*D4] + an) + rr*gh[k + 2*D4]);
            ws[WS_HSEQ + (size_t)(t+1)*D4 + k] = (1.f - zz)*nn + zz*hprev[k];
        }
    }
}

// ---------------- logits GEMM: out[t][v] = w_o[v] . r_t ; track rowmax ----------------
__global__ void k_logits(const float* __restrict__ wo, float* __restrict__ out,
                         float* __restrict__ ws){
    __shared__ float rtile[128*L];  // 32 KB
    int tid = threadIdx.x, lane = tid & 63, warp = tid >> 6;
    int vbase = blockIdx.x * 32;
    float acc[8];
#pragma unroll
    for (int i = 0; i < 8; i++) acc[i] = 0.f;
    const float* rT = ws + WS_RT;
    for (int kc = 0; kc < 4; kc++){
        __syncthreads();
        for (int x = tid; x < 128*L; x += blockDim.x)
            rtile[x] = rT[kc*128*L + x];
        __syncthreads();
#pragma unroll
        for (int vi = 0; vi < 8; vi++){
            int v = vbase + warp*8 + vi;
            const float* w = wo + (size_t)v*H + kc*128;
            float a = acc[vi];
#pragma unroll
            for (int u = 0; u < 128; u += 4){
                float4 wv = *(const float4*)(w + u);
                a += wv.x * rtile[(u+0)*L + lane];
                a += wv.y * rtile[(u+1)*L + lane];
                a += wv.z * rtile[(u+2)*L + lane];
                a += wv.w * rtile[(u+3)*L + lane];
            }
            acc[vi] = a;
        }
    }
    float m = -3.402823466e38f;
#pragma unroll
    for (int vi = 0; vi < 8; vi++){
        int v = vbase + warp*8 + vi;
        out[(size_t)lane*V + v] = acc[vi];
        m = fmaxf(m, acc[vi]);
    }
    atomicMax(((unsigned*)(ws + WS_ROWMAX)) + lane, enc_f(m));
}

// ---------------- exp + row sums ----------------
__global__ void k_exp(float* __restrict__ out, float* __restrict__ ws){
    int nw = gridDim.x * (blockDim.x >> 6);
    int wid = blockIdx.x * (blockDim.x >> 6) + (threadIdx.x >> 6);
    int lane = threadIdx.x & 63;
    const unsigned* rmax = (const unsigned*)(ws + WS_ROWMAX);
    const int nchunk = (L*V)/64;   // 32000, V%64==0 so each chunk is one row t
    for (int c = wid; c < nchunk; c += nw){
        int base = c*64;
        int t = base / V;
        float x = out[base + lane];
        float e = expf(x - dec_f(rmax[t]));
        out[base + lane] = e;
        float s = warpSum64(e);
        if (lane == 0) atomicAdd(ws + WS_ROWSUM + t, s);
    }
}

// ---------------- normalize ----------------
__global__ void k_norm(float* __restrict__ out, const float* __restrict__ ws){
    int i = blockIdx.x*blockDim.x + threadIdx.x;
    int base = i*4;
    if (base < L*V){
        int t = base / V;
        float inv = 1.f / ws[WS_ROWSUM + t];
        float4 p = *(float4*)(out + base);
        p.x *= inv; p.y *= inv; p.z *= inv; p.w *= inv;
        *(float4*)(out + base) = p;
    }
}

extern "C" void kernel_launch(void* const* d_in, const int* in_sizes, int n_in,
                              void* d_out, int out_size, void* d_ws, size_t ws_size,
                              hipStream_t stream){
    const float* hq  = (const float*)d_in[0];
    const float* hp  = (const float*)d_in[1];
    const float* ans = (const float*)d_in[2];
    const float* vw  = (const float*)d_in[3];
    const float* wdw = (const float*)d_in[4];
    const float* wdb = (const float*)d_in[5];
    const float* waw = (const float*)d_in[6];
    const float* uaw = (const float*)d_in[7];
    const float* wrw = (const float*)d_in[8];
    const float* urw = (const float*)d_in[9];
    const float* vrw = (const float*)d_in[10];
    const float* wo  = (const float*)d_in[11];
    const float* wih = (const float*)d_in[12];
    const float* whh = (const float*)d_in[13];
    const float* bih = (const float*)d_in[14];
    const float* bhh = (const float*)d_in[15];
    float* out = (float*)d_out;
    float* ws  = (float*)d_ws;

    k_init<<<L+1, 256, 0, stream>>>(ans, ws);
    k_colsum<<<256, 256, 0, stream>>>(hq, hp, ws);
    k_uah_d0<<<768, 256, 0, stream>>>(uaw, wdw, wdb, hq, hp, ws);
    k_pregemm<<<1792, 256, 0, stream>>>(wih, bih, wrw, ws);

    for (int t = 0; t <= L; t++){
        k_step_p1<<<1024, 256, 0, stream>>>(whh, bhh, waw, vw, urw, vrw, ws, t);
        if (t < L) k_step_p2<<<512, 256, 0, stream>>>(wih, ws, t);
    }

    k_logits<<<1000, 256, 0, stream>>>(wo, out, ws);
    k_exp<<<512, 256, 0, stream>>>(out, ws);
    k_norm<<<2000, 256, 0, stream>>>(out, ws);
}

// Round 2
// 3055.991 us; speedup vs baseline: 3.4855x; 3.4855x over previous
//
#include <hip/hip_runtime.h>
#include <math.h>

#define H 512
#define D2 1024
#define D4 2048
#define E 1024
#define V 32000
#define M 32
#define N 4096
#define L 64
#define G3 (3*D4)   // 6144

// workspace layout (float offsets)
#define WS_H        0                      // 1024
#define WS_UAH      1024                   // 1024
#define WS_HSEQ     2048                   // 65*2048 = 133120
#define WS_GIW      135168                 // 64*6144 (dead after steps; overlaid by BLOCKMAX)
#define WS_RW       528384                 // 64*1024
#define WS_GH       593920                 // 6144
#define WS_SPART    600064                 // 2 parities * 64
#define WS_RSEQ     600192                 // 64*512
#define WS_RT       632960                 // 512*64  (transposed r for logits GEMM)
#define WS_ANST     665728                 // 1024*64 (ans transposed)
#define WS_BLOCKMAX WS_GIW                 // 64 rows * 256 (250 used) block maxima

__device__ __forceinline__ float warpSum64(float v){
#pragma unroll
    for (int off = 32; off; off >>= 1) v += __shfl_xor(v, off, 64);
    return v;
}

// ---------------- init: transpose ans, zero h ----------------
__global__ void k_init(const float* __restrict__ ans, float* __restrict__ ws){
    int b = blockIdx.x;
    if (b < L){
        for (int j = threadIdx.x; j < E; j += blockDim.x)
            ws[WS_ANST + j*L + b] = ans[b*E + j];
    } else {
        for (int i = threadIdx.x; i < D2; i += blockDim.x) ws[WS_H + i] = 0.f;
    }
}

// ---------------- h = colsum(h_q) + colsum(h_p) ----------------
__global__ void k_colsum(const float* __restrict__ hq, const float* __restrict__ hp,
                         float* __restrict__ ws){
    float4 acc = {0.f,0.f,0.f,0.f};
    int tid = threadIdx.x;   // 256 threads -> 1024 cols as float4
    for (int r = blockIdx.x; r < M + N; r += gridDim.x){
        const float* src = (r < M) ? (hq + (size_t)r*D2) : (hp + (size_t)(r-M)*D2);
        float4 v = ((const float4*)src)[tid];
        acc.x += v.x; acc.y += v.y; acc.z += v.z; acc.w += v.w;
    }
    float* h = ws + WS_H + tid*4;
    atomicAdd(h+0, acc.x); atomicAdd(h+1, acc.y);
    atomicAdd(h+2, acc.z); atomicAdd(h+3, acc.w);
}

// ---------------- u_a_h and d0 ----------------
__global__ __launch_bounds__(256) void k_uah_d0(
        const float* __restrict__ uaw, const float* __restrict__ wdw,
        const float* __restrict__ wdb, const float* __restrict__ hq,
        const float* __restrict__ hp, float* __restrict__ ws){
    int wid = blockIdx.x * (blockDim.x >> 6) + (threadIdx.x >> 6); // 0..3071
    int lane = threadIdx.x & 63;
    const float* Wrow; const float* x;
    if (wid < D2){ Wrow = uaw + (size_t)wid*D2; x = ws + WS_H; }
    else {
        int i = (wid - D2) & 1023;
        int r = (wid - D2) >> 10;
        Wrow = wdw + (size_t)i*D2;
        x = r ? hp : hq;  // row 0 of each
    }
    const float4* W4 = (const float4*)Wrow;
    const float4* x4 = (const float4*)x;
    float acc = 0.f;
#pragma unroll
    for (int m = 0; m < 4; m++){
        int j = lane + 64*m;
        float4 w = W4[j], v = x4[j];
        acc += w.x*v.x + w.y*v.y + w.z*v.z + w.w*v.w;
    }
    acc = warpSum64(acc);
    if (lane == 0){
        if (wid < D2) ws[WS_UAH + wid] = acc;
        else {
            int i = (wid - D2) & 1023, r = (wid - D2) >> 10;
            ws[WS_HSEQ + r*D2 + i] = tanhf(acc + wdb[i]);
        }
    }
}

// ---------------- precompute GI_w[t][k] = W_ih[k,:1024]@w_t + b_ih[k]; R_w[t][i] = w_r[i]@w_t ----------------
__global__ __launch_bounds__(256) void k_pregemm(
        const float* __restrict__ wih, const float* __restrict__ bih,
        const float* __restrict__ wrw, float* __restrict__ ws){
    int wid = blockIdx.x * (blockDim.x >> 6) + (threadIdx.x >> 6); // 0..7167
    int lane = threadIdx.x & 63;  // lane = t
    const float* Wrow; float bias = 0.f;
    if (wid < G3){ Wrow = wih + (size_t)wid*D4; bias = bih[wid]; }
    else         { Wrow = wrw + (size_t)(wid - G3)*D2; }
    const float* ansT = ws + WS_ANST;
    float acc = 0.f;
    for (int j = 0; j < E; j += 4){
        float4 wv = *(const float4*)(Wrow + j);   // wave-uniform -> scalar loads
        acc += wv.x * ansT[(j+0)*L + lane];
        acc += wv.y * ansT[(j+1)*L + lane];
        acc += wv.z * ansT[(j+2)*L + lane];
        acc += wv.w * ansT[(j+3)*L + lane];
    }
    acc += bias;
    if (wid < G3) ws[WS_GIW + (size_t)lane*G3 + wid] = acc;
    else          ws[WS_RW  + (size_t)lane*D2 + (wid - G3)] = acc;
}

// ---------------- per-step kernel 1: gh(t), s(t) partials, finalize r_{t-1} ----------------
__global__ __launch_bounds__(256) void k_step_p1(
        const float* __restrict__ whh, const float* __restrict__ bhh,
        const float* __restrict__ waw, const float* __restrict__ vw,
        const float* __restrict__ urw, const float* __restrict__ vrw,
        float* __restrict__ ws, int t){
    int nwaves = gridDim.x * (blockDim.x >> 6);
    int wid = blockIdx.x * (blockDim.x >> 6) + (threadIdx.x >> 6);
    int lane = threadIdx.x & 63;
    const float* hprev = ws + WS_HSEQ + (size_t)t*D4;
    const float4* hp4 = (const float4*)hprev;
    int nA = (t < L) ? G3 : 0;
    int nB = (t < L) ? 64 : 0;
    int nC = (t > 0) ? 512 : 0;
    int ntask = nA + nB + nC;
    for (int task = wid; task < ntask; task += nwaves){
        if (task < nA){
            int k = task;
            const float4* W4 = (const float4*)(whh + (size_t)k*D4);
            float acc = 0.f;
#pragma unroll
            for (int m = 0; m < 8; m++){
                int j = lane + 64*m;
                float4 w = W4[j], h = hp4[j];
                acc += w.x*h.x + w.y*h.y + w.z*h.z + w.w*h.w;
            }
            acc = warpSum64(acc);
            if (lane == 0) ws[WS_GH + k] = acc + bhh[k];
        } else if (task < nA + nB){
            int g = task - nA;
            int r  = g >> 5;
            int i0 = (g & 31) * 32;
            const float4* d4 = (const float4*)(hprev + r*D2);
            float part = 0.f;
            for (int ii = 0; ii < 32; ii++){
                int i = i0 + ii;
                const float4* W4 = (const float4*)(waw + (size_t)i*D2);
                float acc = 0.f;
#pragma unroll
                for (int m = 0; m < 4; m++){
                    int j = lane + 64*m;
                    float4 w = W4[j], d = d4[j];
                    acc += w.x*d.x + w.y*d.y + w.z*d.z + w.w*d.w;
                }
                acc = warpSum64(acc);
                if (lane == 0) part += vw[i] * tanhf(acc + ws[WS_UAH + i]);
            }
            if (lane == 0) ws[WS_SPART + (t & 1)*64 + g] = part;
        } else {
            int h = task - nA - nB;   // 0..511, finalize r_{t-1}
            const float4* dp4 = (const float4*)(ws + WS_HSEQ + (size_t)(t-1)*D4);
            const float4* hn4 = (const float4*)(ws + WS_HSEQ + (size_t)t*D4);
            float sv = ws[WS_SPART + ((t-1) & 1)*64 + lane];
#pragma unroll
            for (int off = 16; off; off >>= 1) sv += __shfl_xor(sv, off, 64);
            float s0 = __shfl(sv, 0, 64), s1 = __shfl(sv, 32, 64);
            float mx = fmaxf(s0, s1);
            float e0 = expf(s0 - mx), e1 = expf(s1 - mx);
            float a0 = e0/(e0+e1), a1 = e1/(e0+e1);
            float acc1 = 0.f, acc2 = 0.f;
            const float4* U14 = (const float4*)(urw + (size_t)h*D2);
            const float4* U24 = (const float4*)(urw + (size_t)(h+H)*D2);
#pragma unroll
            for (int m = 0; m < 4; m++){
                int j = lane + 64*m;
                float4 da = dp4[j], db = dp4[256 + j];
                float4 c; c.x = a0*da.x + a1*db.x; c.y = a0*da.y + a1*db.y;
                          c.z = a0*da.z + a1*db.z; c.w = a0*da.w + a1*db.w;
                float4 u1 = U14[j], u2 = U24[j];
                acc1 += u1.x*c.x + u1.y*c.y + u1.z*c.z + u1.w*c.w;
                acc2 += u2.x*c.x + u2.y*c.y + u2.z*c.z + u2.w*c.w;
            }
            const float4* V14 = (const float4*)(vrw + (size_t)h*D4);
            const float4* V24 = (const float4*)(vrw + (size_t)(h+H)*D4);
#pragma unroll
            for (int m = 0; m < 8; m++){
                int j = lane + 64*m;
                float4 hv = hn4[j];
                float4 v1 = V14[j], v2 = V24[j];
                acc1 += v1.x*hv.x + v1.y*hv.y + v1.z*hv.z + v1.w*hv.w;
                acc2 += v2.x*hv.x + v2.y*hv.y + v2.z*hv.z + v2.w*hv.w;
            }
            acc1 = warpSum64(acc1); acc2 = warpSum64(acc2);
            if (lane == 0){
                float r1 = ws[WS_RW + (size_t)(t-1)*D2 + h]     + acc1;
                float r2 = ws[WS_RW + (size_t)(t-1)*D2 + h + H] + acc2;
                float mo = fmaxf(r1, r2);
                ws[WS_RSEQ + (size_t)(t-1)*H + h] = mo;
                ws[WS_RT + (size_t)h*L + (t-1)]   = mo;
            }
        }
    }
}

// ---------------- per-step kernel 2: h_new(t) ----------------
__global__ __launch_bounds__(256) void k_step_p2(const float* __restrict__ wih,
                                                 float* __restrict__ ws, int t){
    __shared__ float4 cbuf[256];
    __shared__ float sa[2];
    int tid = threadIdx.x;
    int lane = tid & 63, warp = tid >> 6;
    const float* hprev = ws + WS_HSEQ + (size_t)t*D4;
    const float4* hp4 = (const float4*)hprev;
    if (warp == 0){
        float sv = ws[WS_SPART + (t & 1)*64 + lane];
#pragma unroll
        for (int off = 16; off; off >>= 1) sv += __shfl_xor(sv, off, 64);
        if (lane == 0)  sa[0] = sv;
        if (lane == 32) sa[1] = sv;
    }
    __syncthreads();
    float s0 = sa[0], s1 = sa[1];
    float mx = fmaxf(s0, s1);
    float e0 = expf(s0 - mx), e1 = expf(s1 - mx);
    float a0 = e0/(e0+e1), a1 = e1/(e0+e1);
    {
        float4 da = hp4[tid], db = hp4[256 + tid];
        float4 c; c.x = a0*da.x + a1*db.x; c.y = a0*da.y + a1*db.y;
                  c.z = a0*da.z + a1*db.z; c.w = a0*da.w + a1*db.w;
        cbuf[tid] = c;
    }
    __syncthreads();
    int k = blockIdx.x * (blockDim.x >> 6) + warp;  // 0..2047
    if (k < D4){
        const float4* Wr = (const float4*)wih + (size_t)k*512 + 256;
        const float4* Wz = (const float4*)wih + (size_t)(k + D4)*512 + 256;
        const float4* Wn = (const float4*)wih + (size_t)(k + 2*D4)*512 + 256;
        float ar = 0.f, az = 0.f, an = 0.f;
#pragma unroll
        for (int m = 0; m < 4; m++){
            int j = lane + 64*m;
            float4 c = cbuf[j];
            float4 wr = Wr[j], wz = Wz[j], wn = Wn[j];
            ar += wr.x*c.x + wr.y*c.y + wr.z*c.z + wr.w*c.w;
            az += wz.x*c.x + wz.y*c.y + wz.z*c.z + wz.w*c.w;
            an += wn.x*c.x + wn.y*c.y + wn.z*c.z + wn.w*c.w;
        }
        ar = warpSum64(ar); az = warpSum64(az); an = warpSum64(an);
        if (lane == 0){
            const float* gi = ws + WS_GIW + (size_t)t*G3;
            const float* gh = ws + WS_GH;
            float rr = 1.f/(1.f + expf(-((gi[k]        + ar) + gh[k])));
            float zz = 1.f/(1.f + expf(-((gi[k + D4]   + az) + gh[k + D4])));
            float nn = tanhf((gi[k + 2*D4] + an) + rr*gh[k + 2*D4]);
            ws[WS_HSEQ + (size_t)(t+1)*D4 + k] = (1.f - zz)*nn + zz*hprev[k];
        }
    }
}

// ---------------- logits GEMM: out[t][v] = w_o[v] . r_t (tiled, coalesced) ----------------
// grid 250, block 256; tile = 64 t x 128 v; per thread 4 t x 8 v
__global__ __launch_bounds__(256) void k_logits(const float* __restrict__ wo,
        float* __restrict__ out, float* __restrict__ ws){
    __shared__ float a_s[64][132];  // [k][v], padded
    __shared__ float b_s[64][68];   // [k][t], padded
    __shared__ float lmax[64][16];  // per-t, per-vgroup maxima
    int tid = threadIdx.x;
    int vbase = blockIdx.x * 128;
    int tg = tid & 15;           // t group
    int vg = tid >> 4;           // v group (0..15)
    int t0 = tg * 4, v0 = vg * 8;
    float acc[4][8];
#pragma unroll
    for (int i = 0; i < 4; i++)
#pragma unroll
        for (int j = 0; j < 8; j++) acc[i][j] = 0.f;

    const float* rT = ws + WS_RT;
    for (int kc = 0; kc < 512; kc += 64){
        __syncthreads();
        // stage A transposed: a_s[k][v] <- wo[vbase+r][kc+c]
        {
            int col = (tid & 15) * 4;
            int rbase = tid >> 4;
#pragma unroll
            for (int it = 0; it < 8; it++){
                int r = it*16 + rbase;
                float4 w = *(const float4*)(wo + (size_t)(vbase + r)*H + kc + col);
                a_s[col+0][r] = w.x; a_s[col+1][r] = w.y;
                a_s[col+2][r] = w.z; a_s[col+3][r] = w.w;
            }
            // stage B: b_s[k][t] <- rT[(kc+k)*64 + t]
#pragma unroll
            for (int it = 0; it < 4; it++){
                int idx = it*256 + tid;
                int k = idx >> 4;
                int c4 = (idx & 15) * 4;
                *(float4*)&b_s[k][c4] = *(const float4*)(rT + (size_t)(kc + k)*L + c4);
            }
        }
        __syncthreads();
#pragma unroll 4
        for (int k = 0; k < 64; k++){
            float4 bb = *(float4*)&b_s[k][t0];
            float4 aa = *(float4*)&a_s[k][v0];
            float4 ab = *(float4*)&a_s[k][v0+4];
            float bv[4] = {bb.x, bb.y, bb.z, bb.w};
            float av[8] = {aa.x, aa.y, aa.z, aa.w, ab.x, ab.y, ab.z, ab.w};
#pragma unroll
            for (int i = 0; i < 4; i++)
#pragma unroll
                for (int j = 0; j < 8; j++) acc[i][j] += bv[i]*av[j];
        }
    }
    // write output (coalesced, full lines per block) + per-t maxima
#pragma unroll
    for (int i = 0; i < 4; i++){
        float m = acc[i][0];
#pragma unroll
        for (int j = 1; j < 8; j++) m = fmaxf(m, acc[i][j]);
        lmax[t0+i][vg] = m;
        float4 o1 = {acc[i][0], acc[i][1], acc[i][2], acc[i][3]};
        float4 o2 = {acc[i][4], acc[i][5], acc[i][6], acc[i][7]};
        float* dst = out + (size_t)(t0+i)*V + vbase + v0;
        *(float4*)dst = o1;
        *(float4*)(dst+4) = o2;
    }
    __syncthreads();
    if (tid < 64){
        float m = lmax[tid][0];
#pragma unroll
        for (int j = 1; j < 16; j++) m = fmaxf(m, lmax[tid][j]);
        ws[WS_BLOCKMAX + (size_t)tid*256 + blockIdx.x] = m;
    }
}

// ---------------- softmax per row: reduce blockmax, exp+sum+normalize in-register ----------------
__global__ __launch_bounds__(1024) void k_softmax(float* __restrict__ out,
                                                  const float* __restrict__ ws){
    __shared__ float red[16];
    __shared__ float bcast;
    int t = blockIdx.x, tid = threadIdx.x;
    int lane = tid & 63, wv = tid >> 6;
    float m = -3.402823466e38f;
    if (tid < 250) m = ws[WS_BLOCKMAX + (size_t)t*256 + tid];
#pragma unroll
    for (int off = 32; off; off >>= 1) m = fmaxf(m, __shfl_xor(m, off, 64));
    if (lane == 0) red[wv] = m;
    __syncthreads();
    if (tid == 0){
        float mm = red[0];
        for (int i = 1; i < 16; i++) mm = fmaxf(mm, red[i]);
        bcast = mm;
    }
    __syncthreads();
    float rmax = bcast;
    float* row = out + (size_t)t*V;
    float4 e[8];
    float s = 0.f;
#pragma unroll
    for (int i = 0; i < 8; i++){
        int idx = tid + i*1024;
        if (idx < V/4){
            float4 x = ((const float4*)row)[idx];
            e[i].x = expf(x.x - rmax); e[i].y = expf(x.y - rmax);
            e[i].z = expf(x.z - rmax); e[i].w = expf(x.w - rmax);
            s += e[i].x + e[i].y + e[i].z + e[i].w;
        }
    }
#pragma unroll
    for (int off = 32; off; off >>= 1) s += __shfl_xor(s, off, 64);
    if (lane == 0) red[wv] = s;
    __syncthreads();
    if (tid == 0){
        float ss = 0.f;
        for (int i = 0; i < 16; i++) ss += red[i];
        bcast = 1.f/ss;
    }
    __syncthreads();
    float inv = bcast;
#pragma unroll
    for (int i = 0; i < 8; i++){
        int idx = tid + i*1024;
        if (idx < V/4){
            float4 p = e[i];
            p.x *= inv; p.y *= inv; p.z *= inv; p.w *= inv;
            ((float4*)row)[idx] = p;
        }
    }
}

extern "C" void kernel_launch(void* const* d_in, const int* in_sizes, int n_in,
                              void* d_out, int out_size, void* d_ws, size_t ws_size,
                              hipStream_t stream){
    const float* hq  = (const float*)d_in[0];
    const float* hp  = (const float*)d_in[1];
    const float* ans = (const float*)d_in[2];
    const float* vw  = (const float*)d_in[3];
    const float* wdw = (const float*)d_in[4];
    const float* wdb = (const float*)d_in[5];
    const float* waw = (const float*)d_in[6];
    const float* uaw = (const float*)d_in[7];
    const float* wrw = (const float*)d_in[8];
    const float* urw = (const float*)d_in[9];
    const float* vrw = (const float*)d_in[10];
    const float* wo  = (const float*)d_in[11];
    const float* wih = (const float*)d_in[12];
    const float* whh = (const float*)d_in[13];
    const float* bih = (const float*)d_in[14];
    const float* bhh = (const float*)d_in[15];
    float* out = (float*)d_out;
    float* ws  = (float*)d_ws;

    k_init<<<L+1, 256, 0, stream>>>(ans, ws);
    k_colsum<<<256, 256, 0, stream>>>(hq, hp, ws);
    k_uah_d0<<<768, 256, 0, stream>>>(uaw, wdw, wdb, hq, hp, ws);
    k_pregemm<<<1792, 256, 0, stream>>>(wih, bih, wrw, ws);

    for (int t = 0; t <= L; t++){
        k_step_p1<<<1680, 256, 0, stream>>>(whh, bhh, waw, vw, urw, vrw, ws, t);
        if (t < L) k_step_p2<<<512, 256, 0, stream>>>(wih, ws, t);
    }

    k_logits<<<250, 256, 0, stream>>>(wo, out, ws);
    k_softmax<<<64, 1024, 0, stream>>>(out, ws);
}

// Round 4
// 1711.464 us; speedup vs baseline: 6.2238x; 1.7856x over previous
//
#include <hip/hip_runtime.h>
#include <math.h>

#define H 512
#define D2 1024
#define D4 2048
#define E 1024
#define V 32000
#define M 32
#define N 4096
#define L 64
#define G3 (3*D4)   // 6144

// workspace layout (float offsets)
#define WS_H        0                      // 1024
#define WS_UAH      1024                   // 1024
#define WS_HSEQ     2048                   // 65*2048 = 133120
#define WS_GIW      135168                 // 64*6144 = 393216 (dead after steps; overlaid by BLOCKMAX)
#define WS_RW       528384                 // 64*1024 = 65536
#define WS_GH2      593920                 // 2 parity * 6144
#define WS_GIC0     606208                 // 2 * 6144
#define WS_GIC1     618496                 // 2 * 6144
#define WS_URC0     630784                 // 2 * 1024
#define WS_URC1     632832                 // 2 * 1024
#define WS_SP0      634880                 // 2 * 256
#define WS_SP1      635392                 // 2 * 256
#define WS_RT       635904                 // 512*64 (transposed r for logits GEMM)
#define WS_ANST     668672                 // 1024*64 (ans transposed)
#define WS_BLOCKMAX WS_GIW                 // 64 rows * 256 block maxima (logits phase)

__device__ __forceinline__ float warpSum64(float v){
#pragma unroll
    for (int off = 32; off; off >>= 1) v += __shfl_xor(v, off, 64);
    return v;
}
__device__ __forceinline__ float dot4(float4 a, float4 b){
    return a.x*b.x + a.y*b.y + a.z*b.z + a.w*b.w;
}

// ---------------- init: transpose ans, zero h ----------------
__global__ void k_init(const float* __restrict__ ans, float* __restrict__ ws){
    int b = blockIdx.x;
    if (b < L){
        for (int j = threadIdx.x; j < E; j += blockDim.x)
            ws[WS_ANST + j*L + b] = ans[b*E + j];
    } else {
        for (int i = threadIdx.x; i < D2; i += blockDim.x) ws[WS_H + i] = 0.f;
    }
}

// ---------------- h = colsum(h_q) + colsum(h_p) ----------------
__global__ void k_colsum(const float* __restrict__ hq, const float* __restrict__ hp,
                         float* __restrict__ ws){
    float4 acc = {0.f,0.f,0.f,0.f};
    int tid = threadIdx.x;   // 256 threads -> 1024 cols as float4
    for (int r = blockIdx.x; r < M + N; r += gridDim.x){
        const float* src = (r < M) ? (hq + (size_t)r*D2) : (hp + (size_t)(r-M)*D2);
        float4 v = ((const float4*)src)[tid];
        acc.x += v.x; acc.y += v.y; acc.z += v.z; acc.w += v.w;
    }
    float* h = ws + WS_H + tid*4;
    atomicAdd(h+0, acc.x); atomicAdd(h+1, acc.y);
    atomicAdd(h+2, acc.z); atomicAdd(h+3, acc.w);
}

// ---------------- u_a_h and d0 ----------------
__global__ __launch_bounds__(256) void k_uah_d0(
        const float* __restrict__ uaw, const float* __restrict__ wdw,
        const float* __restrict__ wdb, const float* __restrict__ hq,
        const float* __restrict__ hp, float* __restrict__ ws){
    int wid = blockIdx.x * (blockDim.x >> 6) + (threadIdx.x >> 6); // 0..3071
    int lane = threadIdx.x & 63;
    const float* Wrow; const float* x;
    if (wid < D2){ Wrow = uaw + (size_t)wid*D2; x = ws + WS_H; }
    else {
        int i = (wid - D2) & 1023;
        int r = (wid - D2) >> 10;
        Wrow = wdw + (size_t)i*D2;
        x = r ? hp : hq;  // row 0 of each
    }
    const float4* W4 = (const float4*)Wrow;
    const float4* x4 = (const float4*)x;
    float acc = 0.f;
#pragma unroll
    for (int m = 0; m < 4; m++){
        int j = lane + 64*m;
        acc += dot4(W4[j], x4[j]);
    }
    acc = warpSum64(acc);
    if (lane == 0){
        if (wid < D2) ws[WS_UAH + wid] = acc;
        else {
            int i = (wid - D2) & 1023, r = (wid - D2) >> 10;
            ws[WS_HSEQ + r*D2 + i] = tanhf(acc + wdb[i]);
        }
    }
}

// ---------------- pregemm as tiled GEMM ----------------
// C[7168][64] = W[7168][1024] @ ansT[1024][64]
// rows 0..6143: wih w-half (stride D4) -> GIW (+bias);  rows 6144..7167: wrw (stride D2) -> RW
__global__ __launch_bounds__(256) void k_pregemm(
        const float* __restrict__ wih, const float* __restrict__ bih,
        const float* __restrict__ wrw, float* __restrict__ ws){
    __shared__ float a_s[64][68];   // [k][row]
    __shared__ float b_s[64][68];   // [k][t]
    int tid = threadIdx.x;
    int blk = blockIdx.x;
    bool isW = blk < 96;
    const float* src = isW ? wih : wrw;
    size_t stride = isW ? D4 : D2;
    int rbase = isW ? blk*64 : (blk-96)*64;
    int t0 = (tid & 15) * 4;
    int r0 = (tid >> 4) * 4;
    float acc[4][4];
#pragma unroll
    for (int i = 0; i < 4; i++)
#pragma unroll
        for (int j = 0; j < 4; j++) acc[i][j] = 0.f;

    const float* ansT = ws + WS_ANST;
    for (int kc = 0; kc < 1024; kc += 64){
        __syncthreads();
#pragma unroll
        for (int it = 0; it < 4; it++){
            int idx = it*256 + tid;
            int row = idx >> 4;
            int kq  = (idx & 15) * 4;
            float4 w = *(const float4*)(src + (size_t)(rbase + row)*stride + kc + kq);
            a_s[kq+0][row] = w.x; a_s[kq+1][row] = w.y;
            a_s[kq+2][row] = w.z; a_s[kq+3][row] = w.w;
        }
#pragma unroll
        for (int it = 0; it < 4; it++){
            int idx = it*256 + tid;
            int k = idx >> 4;
            int c4 = (idx & 15) * 4;
            *(float4*)&b_s[k][c4] = *(const float4*)(ansT + (size_t)(kc + k)*L + c4);
        }
        __syncthreads();
#pragma unroll 4
        for (int k = 0; k < 64; k++){
            float4 bb = *(float4*)&b_s[k][t0];
            float4 aa = *(float4*)&a_s[k][r0];
            float bv[4] = {bb.x, bb.y, bb.z, bb.w};
            float av[4] = {aa.x, aa.y, aa.z, aa.w};
#pragma unroll
            for (int i = 0; i < 4; i++)
#pragma unroll
                for (int j = 0; j < 4; j++) acc[i][j] += bv[i]*av[j];
        }
    }
#pragma unroll
    for (int i = 0; i < 4; i++){
#pragma unroll
        for (int j = 0; j < 4; j++){
            int r = rbase + r0 + j;
            if (isW) ws[WS_GIW + (size_t)(t0+i)*G3 + r] = acc[i][j] + bih[r];
            else     ws[WS_RW  + (size_t)(t0+i)*D2 + r] = acc[i][j];   // FIX: r already rebased
        }
    }
}

// ---------------- fused step kernel: one launch per step ----------------
#define STEP_BLOCKS 256
#define STEP_THREADS 1024
#define NWAVES (STEP_BLOCKS*16)
__global__ __launch_bounds__(1024) void k_step(
        const float* __restrict__ whh, const float* __restrict__ bhh,
        const float* __restrict__ wih, const float* __restrict__ waw,
        const float* __restrict__ vw,  const float* __restrict__ urw,
        const float* __restrict__ vrw, float* __restrict__ ws, int t){
    __shared__ float4 h4s[D4/4];
    __shared__ float red[16];
    __shared__ float sa[2];
    float* h_lds = (float*)h4s;
    int tid = threadIdx.x, lane = tid & 63, wv = tid >> 6;
    int par = t & 1, pprev = par ^ 1;

    // ---- a(t-1) from spart(t-1) ----
    if (t >= 1){
        if (wv < 8){
            float x = ws[(wv < 4 ? WS_SP0 : WS_SP1) + pprev*256 + (wv & 3)*64 + lane];
            x = warpSum64(x);
            if (lane == 0) red[wv] = x;
        }
        __syncthreads();
        if (tid == 0){
            float s0 = red[0]+red[1]+red[2]+red[3];
            float s1 = red[4]+red[5]+red[6]+red[7];
            float mx = fmaxf(s0, s1);
            float e0 = expf(s0-mx), e1 = expf(s1-mx);
            sa[0] = e0/(e0+e1); sa[1] = e1/(e0+e1);
        }
        __syncthreads();
    }
    float a0 = (t >= 1) ? sa[0] : 0.f;
    float a1 = (t >= 1) ? sa[1] : 0.f;

    // ---- reconstruct h(t) into LDS ----
    if (t == 0){
        for (int i = tid; i < D4; i += STEP_THREADS) h_lds[i] = ws[WS_HSEQ + i];
    } else {
        const float* hprev = ws + WS_HSEQ + (size_t)(t-1)*D4;
        const float* giw = ws + WS_GIW + (size_t)(t-1)*G3;
        const float* gh  = ws + WS_GH2  + pprev*G3;
        const float* g0  = ws + WS_GIC0 + pprev*G3;
        const float* g1  = ws + WS_GIC1 + pprev*G3;
        for (int k = tid; k < D4; k += STEP_THREADS){
            float gir = giw[k]      + a0*g0[k]      + a1*g1[k];
            float giz = giw[k+D4]   + a0*g0[k+D4]   + a1*g1[k+D4];
            float gin = giw[k+2*D4] + a0*g0[k+2*D4] + a1*g1[k+2*D4];
            float rr = 1.f/(1.f + expf(-(gir + gh[k])));
            float zz = 1.f/(1.f + expf(-(giz + gh[k+D4])));
            float nn = tanhf(gin + rr*gh[k+2*D4]);
            float hv = (1.f - zz)*nn + zz*hprev[k];
            h_lds[k] = hv;
            if (blockIdx.x == 0) ws[WS_HSEQ + (size_t)t*D4 + k] = hv;
        }
    }
    __syncthreads();

    const float4* h4 = (const float4*)h_lds;
    int gw = blockIdx.x*16 + wv;
    // tasks: [0,512) r-final | [512,768) s | [768,1792) urc | [1792,7936) gh | [7936,14080) giC
    for (int task = gw; task < 14080; task += NWAVES){
        if (task < 512){
            if (t < 1) continue;
            int h = task;
            const float4* V1 = (const float4*)(vrw + (size_t)h*D4);
            const float4* V2 = (const float4*)(vrw + (size_t)(h+H)*D4);
            float acc1 = 0.f, acc2 = 0.f;
#pragma unroll
            for (int m = 0; m < 8; m++){
                int j = lane + 64*m;
                float4 hv = h4[j];
                acc1 += dot4(V1[j], hv);
                acc2 += dot4(V2[j], hv);
            }
            acc1 = warpSum64(acc1); acc2 = warpSum64(acc2);
            if (lane == 0){
                float r1 = ws[WS_RW + (size_t)(t-1)*D2 + h]
                         + acc1 + a0*ws[WS_URC0 + pprev*D2 + h]
                                + a1*ws[WS_URC1 + pprev*D2 + h];
                float r2 = ws[WS_RW + (size_t)(t-1)*D2 + h + H]
                         + acc2 + a0*ws[WS_URC0 + pprev*D2 + h + H]
                                + a1*ws[WS_URC1 + pprev*D2 + h + H];
                ws[WS_RT + (size_t)h*L + (t-1)] = fmaxf(r1, r2);
            }
        } else if (task < 768){
            if (t >= L) continue;
            int g = task - 512;      // 256 tasks, 4 rows each, dual halves
            float p0 = 0.f, p1 = 0.f;
            for (int ii = 0; ii < 4; ii++){
                int i = g*4 + ii;
                const float4* W4 = (const float4*)(waw + (size_t)i*D2);
                float ac0 = 0.f, ac1 = 0.f;
#pragma unroll
                for (int m = 0; m < 4; m++){
                    int j = lane + 64*m;
                    float4 w = W4[j];
                    ac0 += dot4(w, h4[j]);
                    ac1 += dot4(w, h4[256 + j]);
                }
                ac0 = warpSum64(ac0); ac1 = warpSum64(ac1);
                if (lane == 0){
                    float u = ws[WS_UAH + i], vv = vw[i];
                    p0 += vv * tanhf(ac0 + u);
                    p1 += vv * tanhf(ac1 + u);
                }
            }
            if (lane == 0){
                ws[WS_SP0 + par*256 + g] = p0;
                ws[WS_SP1 + par*256 + g] = p1;
            }
        } else if (task < 1792){
            if (t >= L) continue;
            int i = task - 768;      // urc dual
            const float4* U4 = (const float4*)(urw + (size_t)i*D2);
            float ac0 = 0.f, ac1 = 0.f;
#pragma unroll
            for (int m = 0; m < 4; m++){
                int j = lane + 64*m;
                float4 u = U4[j];
                ac0 += dot4(u, h4[j]);
                ac1 += dot4(u, h4[256 + j]);
            }
            ac0 = warpSum64(ac0); ac1 = warpSum64(ac1);
            if (lane == 0){
                ws[WS_URC0 + par*D2 + i] = ac0;
                ws[WS_URC1 + par*D2 + i] = ac1;
            }
        } else if (task < 7936){
            if (t >= L) continue;
            int k = task - 1792;     // gh
            const float4* W4 = (const float4*)(whh + (size_t)k*D4);
            float acc = 0.f;
#pragma unroll
            for (int m = 0; m < 8; m++){
                int j = lane + 64*m;
                acc += dot4(W4[j], h4[j]);
            }
            acc = warpSum64(acc);
            if (lane == 0) ws[WS_GH2 + par*G3 + k] = acc + bhh[k];
        } else {
            if (t >= L) continue;
            int k = task - 7936;     // giC dual (wih c-half)
            const float4* W4 = (const float4*)(wih + (size_t)k*D4 + D2);
            float ac0 = 0.f, ac1 = 0.f;
#pragma unroll
            for (int m = 0; m < 4; m++){
                int j = lane + 64*m;
                float4 w = W4[j];
                ac0 += dot4(w, h4[j]);
                ac1 += dot4(w, h4[256 + j]);
            }
            ac0 = warpSum64(ac0); ac1 = warpSum64(ac1);
            if (lane == 0){
                ws[WS_GIC0 + par*G3 + k] = ac0;
                ws[WS_GIC1 + par*G3 + k] = ac1;
            }
        }
    }
}

// ---------------- logits GEMM: out[t][v] = w_o[v] . r_t (tiled, coalesced) ----------------
__global__ __launch_bounds__(256) void k_logits(const float* __restrict__ wo,
        float* __restrict__ out, float* __restrict__ ws){
    __shared__ float a_s[64][132];  // [k][v], padded
    __shared__ float b_s[64][68];   // [k][t], padded
    __shared__ float lmax[64][16];  // per-t, per-vgroup maxima
    int tid = threadIdx.x;
    int vbase = blockIdx.x * 128;
    int tg = tid & 15;
    int vg = tid >> 4;
    int t0 = tg * 4, v0 = vg * 8;
    float acc[4][8];
#pragma unroll
    for (int i = 0; i < 4; i++)
#pragma unroll
        for (int j = 0; j < 8; j++) acc[i][j] = 0.f;

    const float* rT = ws + WS_RT;
    for (int kc = 0; kc < 512; kc += 64){
        __syncthreads();
        {
            int col = (tid & 15) * 4;
            int rbase = tid >> 4;
#pragma unroll
            for (int it = 0; it < 8; it++){
                int r = it*16 + rbase;
                float4 w = *(const float4*)(wo + (size_t)(vbase + r)*H + kc + col);
                a_s[col+0][r] = w.x; a_s[col+1][r] = w.y;
                a_s[col+2][r] = w.z; a_s[col+3][r] = w.w;
            }
#pragma unroll
            for (int it = 0; it < 4; it++){
                int idx = it*256 + tid;
                int k = idx >> 4;
                int c4 = (idx & 15) * 4;
                *(float4*)&b_s[k][c4] = *(const float4*)(rT + (size_t)(kc + k)*L + c4);
            }
        }
        __syncthreads();
#pragma unroll 4
        for (int k = 0; k < 64; k++){
            float4 bb = *(float4*)&b_s[k][t0];
            float4 aa = *(float4*)&a_s[k][v0];
            float4 ab = *(float4*)&a_s[k][v0+4];
            float bv[4] = {bb.x, bb.y, bb.z, bb.w};
            float av[8] = {aa.x, aa.y, aa.z, aa.w, ab.x, ab.y, ab.z, ab.w};
#pragma unroll
            for (int i = 0; i < 4; i++)
#pragma unroll
                for (int j = 0; j < 8; j++) acc[i][j] += bv[i]*av[j];
        }
    }
#pragma unroll
    for (int i = 0; i < 4; i++){
        float m = acc[i][0];
#pragma unroll
        for (int j = 1; j < 8; j++) m = fmaxf(m, acc[i][j]);
        lmax[t0+i][vg] = m;
        float4 o1 = {acc[i][0], acc[i][1], acc[i][2], acc[i][3]};
        float4 o2 = {acc[i][4], acc[i][5], acc[i][6], acc[i][7]};
        float* dst = out + (size_t)(t0+i)*V + vbase + v0;
        *(float4*)dst = o1;
        *(float4*)(dst+4) = o2;
    }
    __syncthreads();
    if (tid < 64){
        float m = lmax[tid][0];
#pragma unroll
        for (int j = 1; j < 16; j++) m = fmaxf(m, lmax[tid][j]);
        ws[WS_BLOCKMAX + (size_t)tid*256 + blockIdx.x] = m;
    }
}

// ---------------- softmax per row ----------------
__global__ __launch_bounds__(1024) void k_softmax(float* __restrict__ out,
                                                  const float* __restrict__ ws){
    __shared__ float red[16];
    __shared__ float bcast;
    int t = blockIdx.x, tid = threadIdx.x;
    int lane = tid & 63, wv = tid >> 6;
    float m = -3.402823466e38f;
    if (tid < 250) m = ws[WS_BLOCKMAX + (size_t)t*256 + tid];
#pragma unroll
    for (int off = 32; off; off >>= 1) m = fmaxf(m, __shfl_xor(m, off, 64));
    if (lane == 0) red[wv] = m;
    __syncthreads();
    if (tid == 0){
        float mm = red[0];
        for (int i = 1; i < 16; i++) mm = fmaxf(mm, red[i]);
        bcast = mm;
    }
    __syncthreads();
    float rmax = bcast;
    float* row = out + (size_t)t*V;
    float4 e[8];
    float s = 0.f;
#pragma unroll
    for (int i = 0; i < 8; i++){
        int idx = tid + i*1024;
        if (idx < V/4){
            float4 x = ((const float4*)row)[idx];
            e[i].x = expf(x.x - rmax); e[i].y = expf(x.y - rmax);
            e[i].z = expf(x.z - rmax); e[i].w = expf(x.w - rmax);
            s += e[i].x + e[i].y + e[i].z + e[i].w;
        }
    }
#pragma unroll
    for (int off = 32; off; off >>= 1) s += __shfl_xor(s, off, 64);
    if (lane == 0) red[wv] = s;
    __syncthreads();
    if (tid == 0){
        float ss = 0.f;
        for (int i = 0; i < 16; i++) ss += red[i];
        bcast = 1.f/ss;
    }
    __syncthreads();
    float inv = bcast;
#pragma unroll
    for (int i = 0; i < 8; i++){
        int idx = tid + i*1024;
        if (idx < V/4){
            float4 p = e[i];
            p.x *= inv; p.y *= inv; p.z *= inv; p.w *= inv;
            ((float4*)row)[idx] = p;
        }
    }
}

extern "C" void kernel_launch(void* const* d_in, const int* in_sizes, int n_in,
                              void* d_out, int out_size, void* d_ws, size_t ws_size,
                              hipStream_t stream){
    const float* hq  = (const float*)d_in[0];
    const float* hp  = (const float*)d_in[1];
    const float* ans = (const float*)d_in[2];
    const float* vw  = (const float*)d_in[3];
    const float* wdw = (const float*)d_in[4];
    const float* wdb = (const float*)d_in[5];
    const float* waw = (const float*)d_in[6];
    const float* uaw = (const float*)d_in[7];
    const float* wrw = (const float*)d_in[8];
    const float* urw = (const float*)d_in[9];
    const float* vrw = (const float*)d_in[10];
    const float* wo  = (const float*)d_in[11];
    const float* wih = (const float*)d_in[12];
    const float* whh = (const float*)d_in[13];
    const float* bih = (const float*)d_in[14];
    const float* bhh = (const float*)d_in[15];
    float* out = (float*)d_out;
    float* ws  = (float*)d_ws;

    k_init<<<L+1, 256, 0, stream>>>(ans, ws);
    k_colsum<<<256, 256, 0, stream>>>(hq, hp, ws);
    k_uah_d0<<<768, 256, 0, stream>>>(uaw, wdw, wdb, hq, hp, ws);
    k_pregemm<<<112, 256, 0, stream>>>(wih, bih, wrw, ws);

    for (int t = 0; t <= L; t++)
        k_step<<<STEP_BLOCKS, STEP_THREADS, 0, stream>>>(whh, bhh, wih, waw, vw, urw, vrw, ws, t);

    k_logits<<<250, 256, 0, stream>>>(wo, out, ws);
    k_softmax<<<64, 1024, 0, stream>>>(out, ws);
}

// Round 5
// 1459.235 us; speedup vs baseline: 7.2996x; 1.1729x over previous
//
#include <hip/hip_runtime.h>
#include <math.h>

#define H 512
#define D2 1024
#define D4 2048
#define E 1024
#define V 32000
#define M 32
#define N 4096
#define L 64
#define G3 (3*D4)   // 6144

// workspace layout (float offsets)
#define WS_H        0                      // 1024
#define WS_UAH      1024                   // 1024
#define WS_HSEQ     2048                   // 65*2048 = 133120
#define WS_GIW      135168                 // 64*6144 = 393216 (dead after steps; overlaid by BLOCKMAX)
#define WS_RW       528384                 // 64*1024 = 65536
#define WS_GH2      593920                 // 2 parity * 6144
#define WS_GIC0     606208                 // 2 * 6144
#define WS_GIC1     618496                 // 2 * 6144
#define WS_URC0     630784                 // 2 * 1024
#define WS_URC1     632832                 // 2 * 1024
#define WS_SP0      634880                 // 2 * 256
#define WS_SP1      635392                 // 2 * 256
#define WS_RT       635904                 // 512*64 (transposed r for logits GEMM)
#define WS_ANST     668672                 // 1024*64 (ans transposed)
#define WS_BLOCKMAX WS_GIW                 // 64 rows * 256 block maxima (logits phase)
// bf16 weight caches (optional, if ws_size permits)
#define WS_WHHB     734208                 // 6144*2048 bf16 = 6291456 floats
#define WS_WIHCB    7025664                // 6144*1024 bf16 = 3145728 floats
#define WS_END_BF   10171392               // total floats with bf16 caches (~40.7 MB)

__device__ __forceinline__ float warpSum64(float v){
#pragma unroll
    for (int off = 32; off; off >>= 1) v += __shfl_xor(v, off, 64);
    return v;
}
__device__ __forceinline__ float dot4(float4 a, float4 b){
    return a.x*b.x + a.y*b.y + a.z*b.z + a.w*b.w;
}
__device__ __forceinline__ unsigned short f2bf(float f){
    unsigned u = __float_as_uint(f);
    u += 0x7fffu + ((u >> 16) & 1u);   // RNE
    return (unsigned short)(u >> 16);
}
__device__ __forceinline__ float bflo(unsigned u){ return __uint_as_float(u << 16); }
__device__ __forceinline__ float bfhi(unsigned u){ return __uint_as_float(u & 0xffff0000u); }

// ---------------- init: transpose ans, zero h ----------------
__global__ void k_init(const float* __restrict__ ans, float* __restrict__ ws){
    int b = blockIdx.x;
    if (b < L){
        for (int j = threadIdx.x; j < E; j += blockDim.x)
            ws[WS_ANST + j*L + b] = ans[b*E + j];
    } else {
        for (int i = threadIdx.x; i < D2; i += blockDim.x) ws[WS_H + i] = 0.f;
    }
}

// ---------------- one-time bf16 conversion of whh + wih c-half ----------------
__global__ __launch_bounds__(256) void k_cvt(const float* __restrict__ whh,
        const float* __restrict__ wih, float* __restrict__ ws){
    size_t idx = (size_t)blockIdx.x*blockDim.x + threadIdx.x;
    size_t nthr = (size_t)gridDim.x*blockDim.x;
    ushort4* dw = (ushort4*)(ws + WS_WHHB);
    const float4* s4 = (const float4*)whh;
    for (size_t i = idx; i < (size_t)G3*D4/4; i += nthr){
        float4 v = s4[i];
        ushort4 o; o.x = f2bf(v.x); o.y = f2bf(v.y); o.z = f2bf(v.z); o.w = f2bf(v.w);
        dw[i] = o;
    }
    ushort4* dc = (ushort4*)(ws + WS_WIHCB);
    const float4* w4 = (const float4*)wih;
    for (size_t i = idx; i < (size_t)G3*D2/4; i += nthr){
        size_t row = i / (D2/4), col = i - row*(D2/4);
        float4 v = w4[row*(D4/4) + (D2/4) + col];
        ushort4 o; o.x = f2bf(v.x); o.y = f2bf(v.y); o.z = f2bf(v.z); o.w = f2bf(v.w);
        dc[i] = o;
    }
}

// ---------------- h = colsum(h_q) + colsum(h_p) ----------------
__global__ void k_colsum(const float* __restrict__ hq, const float* __restrict__ hp,
                         float* __restrict__ ws){
    float4 acc = {0.f,0.f,0.f,0.f};
    int tid = threadIdx.x;
    for (int r = blockIdx.x; r < M + N; r += gridDim.x){
        const float* src = (r < M) ? (hq + (size_t)r*D2) : (hp + (size_t)(r-M)*D2);
        float4 v = ((const float4*)src)[tid];
        acc.x += v.x; acc.y += v.y; acc.z += v.z; acc.w += v.w;
    }
    float* h = ws + WS_H + tid*4;
    atomicAdd(h+0, acc.x); atomicAdd(h+1, acc.y);
    atomicAdd(h+2, acc.z); atomicAdd(h+3, acc.w);
}

// ---------------- u_a_h and d0 ----------------
__global__ __launch_bounds__(256) void k_uah_d0(
        const float* __restrict__ uaw, const float* __restrict__ wdw,
        const float* __restrict__ wdb, const float* __restrict__ hq,
        const float* __restrict__ hp, float* __restrict__ ws){
    int wid = blockIdx.x * (blockDim.x >> 6) + (threadIdx.x >> 6);
    int lane = threadIdx.x & 63;
    const float* Wrow; const float* x;
    if (wid < D2){ Wrow = uaw + (size_t)wid*D2; x = ws + WS_H; }
    else {
        int i = (wid - D2) & 1023;
        int r = (wid - D2) >> 10;
        Wrow = wdw + (size_t)i*D2;
        x = r ? hp : hq;
    }
    const float4* W4 = (const float4*)Wrow;
    const float4* x4 = (const float4*)x;
    float acc = 0.f;
#pragma unroll
    for (int m = 0; m < 4; m++){
        int j = lane + 64*m;
        acc += dot4(W4[j], x4[j]);
    }
    acc = warpSum64(acc);
    if (lane == 0){
        if (wid < D2) ws[WS_UAH + wid] = acc;
        else {
            int i = (wid - D2) & 1023, r = (wid - D2) >> 10;
            ws[WS_HSEQ + r*D2 + i] = tanhf(acc + wdb[i]);
        }
    }
}

// ---------------- pregemm as tiled GEMM (conflict-free, 224 blocks) ----------------
// C[7168][64] = W[7168][1024] @ ansT[1024][64]
// blocks 0..191: wih w-half 32-row tiles -> GIW (+bias); 192..223: wrw -> RW
__global__ __launch_bounds__(256) void k_pregemm(
        const float* __restrict__ wih, const float* __restrict__ bih,
        const float* __restrict__ wrw, float* __restrict__ ws){
    __shared__ float aR[32][68];    // [row][k] row-major: conflict-free stores, broadcast reads
    __shared__ float b_s[64][68];   // [k][t]
    int tid = threadIdx.x;
    int blk = blockIdx.x;
    bool isW = blk < 192;
    const float* src = isW ? wih : wrw;
    size_t stride = isW ? D4 : D2;
    int rbase = isW ? blk*32 : (blk-192)*32;
    int t0 = (tid & 15) * 4;
    int rg = (tid >> 4) * 2;
    float acc[4][2];
#pragma unroll
    for (int i = 0; i < 4; i++){ acc[i][0] = 0.f; acc[i][1] = 0.f; }

    const float* ansT = ws + WS_ANST;
    for (int kc = 0; kc < 1024; kc += 64){
        __syncthreads();
#pragma unroll
        for (int it = 0; it < 2; it++){
            int idx = it*256 + tid;
            int row = idx >> 4;
            int kq  = (idx & 15) * 4;
            float4 w = *(const float4*)(src + (size_t)(rbase + row)*stride + kc + kq);
            *(float4*)&aR[row][kq] = w;
        }
#pragma unroll
        for (int it = 0; it < 4; it++){
            int idx = it*256 + tid;
            int k = idx >> 4;
            int c4 = (idx & 15) * 4;
            *(float4*)&b_s[k][c4] = *(const float4*)(ansT + (size_t)(kc + k)*L + c4);
        }
        __syncthreads();
#pragma unroll 4
        for (int k = 0; k < 64; k++){
            float4 bb = *(float4*)&b_s[k][t0];
            float a0r = aR[rg][k], a1r = aR[rg+1][k];
            acc[0][0] += bb.x*a0r; acc[0][1] += bb.x*a1r;
            acc[1][0] += bb.y*a0r; acc[1][1] += bb.y*a1r;
            acc[2][0] += bb.z*a0r; acc[2][1] += bb.z*a1r;
            acc[3][0] += bb.w*a0r; acc[3][1] += bb.w*a1r;
        }
    }
#pragma unroll
    for (int i = 0; i < 4; i++){
#pragma unroll
        for (int j = 0; j < 2; j++){
            int r = rbase + rg + j;
            if (isW) ws[WS_GIW + (size_t)(t0+i)*G3 + r] = acc[i][j] + bih[r];
            else     ws[WS_RW  + (size_t)(t0+i)*D2 + r] = acc[i][j];
        }
    }
}

// ---------------- fused step kernel: one launch per step ----------------
#define STEP_BLOCKS 256
#define STEP_THREADS 1024
#define NWAVES (STEP_BLOCKS*16)
__global__ __launch_bounds__(1024) void k_step(
        const float* __restrict__ whh, const float* __restrict__ bhh,
        const float* __restrict__ wih, const float* __restrict__ waw,
        const float* __restrict__ vw,  const float* __restrict__ urw,
        const float* __restrict__ vrw, float* __restrict__ ws, int t, int use_bf){
    __shared__ float4 h4s[D4/4];
    __shared__ float red[16];
    __shared__ float sa[2];
    float* h_lds = (float*)h4s;
    int tid = threadIdx.x, lane = tid & 63, wv = tid >> 6;
    int par = t & 1, pprev = par ^ 1;

    // ---- a(t-1) from spart(t-1) ----
    if (t >= 1){
        if (wv < 8){
            float x = ws[(wv < 4 ? WS_SP0 : WS_SP1) + pprev*256 + (wv & 3)*64 + lane];
            x = warpSum64(x);
            if (lane == 0) red[wv] = x;
        }
        __syncthreads();
        if (tid == 0){
            float s0 = red[0]+red[1]+red[2]+red[3];
            float s1 = red[4]+red[5]+red[6]+red[7];
            float mx = fmaxf(s0, s1);
            float e0 = expf(s0-mx), e1 = expf(s1-mx);
            sa[0] = e0/(e0+e1); sa[1] = e1/(e0+e1);
        }
        __syncthreads();
    }
    float a0 = (t >= 1) ? sa[0] : 0.f;
    float a1 = (t >= 1) ? sa[1] : 0.f;

    // ---- reconstruct h(t) into LDS ----
    if (t == 0){
        for (int i = tid; i < D4; i += STEP_THREADS) h_lds[i] = ws[WS_HSEQ + i];
    } else {
        const float* hprev = ws + WS_HSEQ + (size_t)(t-1)*D4;
        const float* giw = ws + WS_GIW + (size_t)(t-1)*G3;
        const float* gh  = ws + WS_GH2  + pprev*G3;
        const float* g0  = ws + WS_GIC0 + pprev*G3;
        const float* g1  = ws + WS_GIC1 + pprev*G3;
        for (int k = tid; k < D4; k += STEP_THREADS){
            float gir = giw[k]      + a0*g0[k]      + a1*g1[k];
            float giz = giw[k+D4]   + a0*g0[k+D4]   + a1*g1[k+D4];
            float gin = giw[k+2*D4] + a0*g0[k+2*D4] + a1*g1[k+2*D4];
            float rr = 1.f/(1.f + expf(-(gir + gh[k])));
            float zz = 1.f/(1.f + expf(-(giz + gh[k+D4])));
            float nn = tanhf(gin + rr*gh[k+2*D4]);
            float hv = (1.f - zz)*nn + zz*hprev[k];
            h_lds[k] = hv;
            if (blockIdx.x == 0) ws[WS_HSEQ + (size_t)t*D4 + k] = hv;
        }
    }
    __syncthreads();

    const float4* h4 = (const float4*)h_lds;
    int gw = blockIdx.x*16 + wv;
    // tasks: [0,512) r-final | [512,768) s | [768,1792) urc | [1792,7936) gh | [7936,14080) giC
    for (int task = gw; task < 14080; task += NWAVES){
        if (task < 512){
            if (t < 1) continue;
            int h = task;
            const float4* V1 = (const float4*)(vrw + (size_t)h*D4);
            const float4* V2 = (const float4*)(vrw + (size_t)(h+H)*D4);
            float acc1 = 0.f, acc2 = 0.f;
#pragma unroll
            for (int m = 0; m < 8; m++){
                int j = lane + 64*m;
                float4 hv = h4[j];
                acc1 += dot4(V1[j], hv);
                acc2 += dot4(V2[j], hv);
            }
            acc1 = warpSum64(acc1); acc2 = warpSum64(acc2);
            if (lane == 0){
                float r1 = ws[WS_RW + (size_t)(t-1)*D2 + h]
                         + acc1 + a0*ws[WS_URC0 + pprev*D2 + h]
                                + a1*ws[WS_URC1 + pprev*D2 + h];
                float r2 = ws[WS_RW + (size_t)(t-1)*D2 + h + H]
                         + acc2 + a0*ws[WS_URC0 + pprev*D2 + h + H]
                                + a1*ws[WS_URC1 + pprev*D2 + h + H];
                ws[WS_RT + (size_t)h*L + (t-1)] = fmaxf(r1, r2);
            }
        } else if (task < 768){
            if (t >= L) continue;
            int g = task - 512;
            float p0 = 0.f, p1 = 0.f;
            for (int ii = 0; ii < 4; ii++){
                int i = g*4 + ii;
                const float4* W4 = (const float4*)(waw + (size_t)i*D2);
                float ac0 = 0.f, ac1 = 0.f;
#pragma unroll
                for (int m = 0; m < 4; m++){
                    int j = lane + 64*m;
                    float4 w = W4[j];
                    ac0 += dot4(w, h4[j]);
                    ac1 += dot4(w, h4[256 + j]);
                }
                ac0 = warpSum64(ac0); ac1 = warpSum64(ac1);
                if (lane == 0){
                    float u = ws[WS_UAH + i], vv = vw[i];
                    p0 += vv * tanhf(ac0 + u);
                    p1 += vv * tanhf(ac1 + u);
                }
            }
            if (lane == 0){
                ws[WS_SP0 + par*256 + g] = p0;
                ws[WS_SP1 + par*256 + g] = p1;
            }
        } else if (task < 1792){
            if (t >= L) continue;
            int i = task - 768;
            const float4* U4 = (const float4*)(urw + (size_t)i*D2);
            float ac0 = 0.f, ac1 = 0.f;
#pragma unroll
            for (int m = 0; m < 4; m++){
                int j = lane + 64*m;
                float4 u = U4[j];
                ac0 += dot4(u, h4[j]);
                ac1 += dot4(u, h4[256 + j]);
            }
            ac0 = warpSum64(ac0); ac1 = warpSum64(ac1);
            if (lane == 0){
                ws[WS_URC0 + par*D2 + i] = ac0;
                ws[WS_URC1 + par*D2 + i] = ac1;
            }
        } else if (task < 7936){
            if (t >= L) continue;
            int k = task - 1792;     // gh
            float acc = 0.f;
            if (use_bf){
                const unsigned short* Wr = (const unsigned short*)(ws + WS_WHHB) + (size_t)k*D4;
#pragma unroll
                for (int m = 0; m < 4; m++){
                    int e = m*512 + lane*8;
                    uint4 w = *(const uint4*)(Wr + e);
                    float4 ha = h4[e>>2], hb = h4[(e>>2)+1];
                    acc += bflo(w.x)*ha.x + bfhi(w.x)*ha.y
                         + bflo(w.y)*ha.z + bfhi(w.y)*ha.w
                         + bflo(w.z)*hb.x + bfhi(w.z)*hb.y
                         + bflo(w.w)*hb.z + bfhi(w.w)*hb.w;
                }
            } else {
                const float4* W4 = (const float4*)(whh + (size_t)k*D4);
#pragma unroll
                for (int m = 0; m < 8; m++){
                    int j = lane + 64*m;
                    acc += dot4(W4[j], h4[j]);
                }
            }
            acc = warpSum64(acc);
            if (lane == 0) ws[WS_GH2 + par*G3 + k] = acc + bhh[k];
        } else {
            if (t >= L) continue;
            int k = task - 7936;     // giC dual (wih c-half)
            float ac0 = 0.f, ac1 = 0.f;
            if (use_bf){
                const unsigned short* Wr = (const unsigned short*)(ws + WS_WIHCB) + (size_t)k*D2;
#pragma unroll
                for (int m = 0; m < 2; m++){
                    int e = m*512 + lane*8;
                    uint4 w = *(const uint4*)(Wr + e);
                    float4 ha = h4[e>>2],       hb = h4[(e>>2)+1];
                    float4 hc = h4[256+(e>>2)], hd = h4[256+(e>>2)+1];
                    float f0 = bflo(w.x), f1 = bfhi(w.x), f2 = bflo(w.y), f3 = bfhi(w.y);
                    float f4 = bflo(w.z), f5 = bfhi(w.z), f6 = bflo(w.w), f7 = bfhi(w.w);
                    ac0 += f0*ha.x + f1*ha.y + f2*ha.z + f3*ha.w
                         + f4*hb.x + f5*hb.y + f6*hb.z + f7*hb.w;
                    ac1 += f0*hc.x + f1*hc.y + f2*hc.z + f3*hc.w
                         + f4*hd.x + f5*hd.y + f6*hd.z + f7*hd.w;
                }
            } else {
                const float4* W4 = (const float4*)(wih + (size_t)k*D4 + D2);
#pragma unroll
                for (int m = 0; m < 4; m++){
                    int j = lane + 64*m;
                    float4 w = W4[j];
                    ac0 += dot4(w, h4[j]);
                    ac1 += dot4(w, h4[256 + j]);
                }
            }
            ac0 = warpSum64(ac0); ac1 = warpSum64(ac1);
            if (lane == 0){
                ws[WS_GIC0 + par*G3 + k] = ac0;
                ws[WS_GIC1 + par*G3 + k] = ac1;
            }
        }
    }
}

// ---------------- logits GEMM: out[t][v] = w_o[v] . r_t (tiled, coalesced) ----------------
__global__ __launch_bounds__(256) void k_logits(const float* __restrict__ wo,
        float* __restrict__ out, float* __restrict__ ws){
    __shared__ float a_s[64][132];
    __shared__ float b_s[64][68];
    __shared__ float lmax[64][16];
    int tid = threadIdx.x;
    int vbase = blockIdx.x * 128;
    int tg = tid & 15;
    int vg = tid >> 4;
    int t0 = tg * 4, v0 = vg * 8;
    float acc[4][8];
#pragma unroll
    for (int i = 0; i < 4; i++)
#pragma unroll
        for (int j = 0; j < 8; j++) acc[i][j] = 0.f;

    const float* rT = ws + WS_RT;
    for (int kc = 0; kc < 512; kc += 64){
        __syncthreads();
        {
            int col = (tid & 15) * 4;
            int rbase = tid >> 4;
#pragma unroll
            for (int it = 0; it < 8; it++){
                int r = it*16 + rbase;
                float4 w = *(const float4*)(wo + (size_t)(vbase + r)*H + kc + col);
                a_s[col+0][r] = w.x; a_s[col+1][r] = w.y;
                a_s[col+2][r] = w.z; a_s[col+3][r] = w.w;
            }
#pragma unroll
            for (int it = 0; it < 4; it++){
                int idx = it*256 + tid;
                int k = idx >> 4;
                int c4 = (idx & 15) * 4;
                *(float4*)&b_s[k][c4] = *(const float4*)(rT + (size_t)(kc + k)*L + c4);
            }
        }
        __syncthreads();
#pragma unroll 4
        for (int k = 0; k < 64; k++){
            float4 bb = *(float4*)&b_s[k][t0];
            float4 aa = *(float4*)&a_s[k][v0];
            float4 ab = *(float4*)&a_s[k][v0+4];
            float bv[4] = {bb.x, bb.y, bb.z, bb.w};
            float av[8] = {aa.x, aa.y, aa.z, aa.w, ab.x, ab.y, ab.z, ab.w};
#pragma unroll
            for (int i = 0; i < 4; i++)
#pragma unroll
                for (int j = 0; j < 8; j++) acc[i][j] += bv[i]*av[j];
        }
    }
#pragma unroll
    for (int i = 0; i < 4; i++){
        float m = acc[i][0];
#pragma unroll
        for (int j = 1; j < 8; j++) m = fmaxf(m, acc[i][j]);
        lmax[t0+i][vg] = m;
        float4 o1 = {acc[i][0], acc[i][1], acc[i][2], acc[i][3]};
        float4 o2 = {acc[i][4], acc[i][5], acc[i][6], acc[i][7]};
        float* dst = out + (size_t)(t0+i)*V + vbase + v0;
        *(float4*)dst = o1;
        *(float4*)(dst+4) = o2;
    }
    __syncthreads();
    if (tid < 64){
        float m = lmax[tid][0];
#pragma unroll
        for (int j = 1; j < 16; j++) m = fmaxf(m, lmax[tid][j]);
        ws[WS_BLOCKMAX + (size_t)tid*256 + blockIdx.x] = m;
    }
}

// ---------------- softmax per row ----------------
__global__ __launch_bounds__(1024) void k_softmax(float* __restrict__ out,
                                                  const float* __restrict__ ws){
    __shared__ float red[16];
    __shared__ float bcast;
    int t = blockIdx.x, tid = threadIdx.x;
    int lane = tid & 63, wv = tid >> 6;
    float m = -3.402823466e38f;
    if (tid < 250) m = ws[WS_BLOCKMAX + (size_t)t*256 + tid];
#pragma unroll
    for (int off = 32; off; off >>= 1) m = fmaxf(m, __shfl_xor(m, off, 64));
    if (lane == 0) red[wv] = m;
    __syncthreads();
    if (tid == 0){
        float mm = red[0];
        for (int i = 1; i < 16; i++) mm = fmaxf(mm, red[i]);
        bcast = mm;
    }
    __syncthreads();
    float rmax = bcast;
    float* row = out + (size_t)t*V;
    float4 e[8];
    float s = 0.f;
#pragma unroll
    for (int i = 0; i < 8; i++){
        int idx = tid + i*1024;
        if (idx < V/4){
            float4 x = ((const float4*)row)[idx];
            e[i].x = expf(x.x - rmax); e[i].y = expf(x.y - rmax);
            e[i].z = expf(x.z - rmax); e[i].w = expf(x.w - rmax);
            s += e[i].x + e[i].y + e[i].z + e[i].w;
        }
    }
#pragma unroll
    for (int off = 32; off; off >>= 1) s += __shfl_xor(s, off, 64);
    if (lane == 0) red[wv] = s;
    __syncthreads();
    if (tid == 0){
        float ss = 0.f;
        for (int i = 0; i < 16; i++) ss += red[i];
        bcast = 1.f/ss;
    }
    __syncthreads();
    float inv = bcast;
#pragma unroll
    for (int i = 0; i < 8; i++){
        int idx = tid + i*1024;
        if (idx < V/4){
            float4 p = e[i];
            p.x *= inv; p.y *= inv; p.z *= inv; p.w *= inv;
            ((float4*)row)[idx] = p;
        }
    }
}

extern "C" void kernel_launch(void* const* d_in, const int* in_sizes, int n_in,
                              void* d_out, int out_size, void* d_ws, size_t ws_size,
                              hipStream_t stream){
    const float* hq  = (const float*)d_in[0];
    const float* hp  = (const float*)d_in[1];
    const float* ans = (const float*)d_in[2];
    const float* vw  = (const float*)d_in[3];
    const float* wdw = (const float*)d_in[4];
    const float* wdb = (const float*)d_in[5];
    const float* waw = (const float*)d_in[6];
    const float* uaw = (const float*)d_in[7];
    const float* wrw = (const float*)d_in[8];
    const float* urw = (const float*)d_in[9];
    const float* vrw = (const float*)d_in[10];
    const float* wo  = (const float*)d_in[11];
    const float* wih = (const float*)d_in[12];
    const float* whh = (const float*)d_in[13];
    const float* bih = (const float*)d_in[14];
    const float* bhh = (const float*)d_in[15];
    float* out = (float*)d_out;
    float* ws  = (float*)d_ws;

    int use_bf = (ws_size >= (size_t)WS_END_BF * 4) ? 1 : 0;

    k_init<<<L+1, 256, 0, stream>>>(ans, ws);
    if (use_bf) k_cvt<<<1024, 256, 0, stream>>>(whh, wih, ws);
    k_colsum<<<256, 256, 0, stream>>>(hq, hp, ws);
    k_uah_d0<<<768, 256, 0, stream>>>(uaw, wdw, wdb, hq, hp, ws);
    k_pregemm<<<224, 256, 0, stream>>>(wih, bih, wrw, ws);

    for (int t = 0; t <= L; t++)
        k_step<<<STEP_BLOCKS, STEP_THREADS, 0, stream>>>(whh, bhh, wih, waw, vw, urw, vrw, ws, t, use_bf);

    k_logits<<<250, 256, 0, stream>>>(wo, out, ws);
    k_softmax<<<64, 1024, 0, stream>>>(out, ws);
}